// Round 19
// baseline (388.544 us; speedup 1.0000x reference)
//
#include <hip/hip_runtime.h>
#include <math.h>
#include <stdint.h>

#define K_DIM 8192     // S*DIM
#define D_DIM 2048
#define M_ROWS 8192
#define N_W 32         // W columns (only 24 used in H)
#define NC 24
#define RB 4           // rows per block (gemm)
#define THR 256

typedef float f32x4 __attribute__((ext_vector_type(4)));

// Wq layout (uint4): [g(96)][t(256)], g = (i*4+e)*3 + j4.
// Thread t's k-set: k = i*1024 + 4t + e (i<8, e<4). Entry (g,t) packs W cols
// [j4*8 .. j4*8+7] of row k as 4 u32 (2 rne-bf16 each: low16=col 2m,
// high16=col 2m+1). Consecutive t -> consecutive uint4 = coalesced L2 stream.
// Total 96*256*16B = 393,216 B (L2-resident).

// ---------------------------------------------------------------------------
// Kernel 0: prepack W -> packed rne-bf16 pairs, thread per k.
// ---------------------------------------------------------------------------
__global__ __launch_bounds__(256) void mhc_prepack_kernel(
    const float* __restrict__ W, uint4* __restrict__ Wq)
{
    const int k = blockIdx.x * 256 + threadIdx.x;   // 0..8191
    const int i = k >> 10, e = k & 3, t = (k >> 2) & 255;
    const float* wr = W + (size_t)k * N_W;
#pragma unroll
    for (int j4 = 0; j4 < 3; ++j4) {
        uint32_t u[4];
#pragma unroll
        for (int m = 0; m < 4; ++m) {
            uint32_t a = __float_as_uint(wr[j4 * 8 + 2 * m]);
            uint32_t b = __float_as_uint(wr[j4 * 8 + 2 * m + 1]);
            a = a + 0x7FFFu + ((a >> 16) & 1u);     // rne to bf16
            b = b + 0x7FFFu + ((b >> 16) & 1u);
            u[m] = (b & 0xFFFF0000u) | (a >> 16);
        }
        Wq[(size_t)(((i * 4 + e) * 3) + j4) * 256 + t] =
            make_uint4(u[0], u[1], u[2], u[3]);
    }
}

// ---------------------------------------------------------------------------
// Kernel 1: H[m,0:24] = X @ W (W rne-bf16, X exact f32) — APPLY-SHAPED:
// 2048 blocks x 256 thr, no LDS/barriers in the hot loop, per-thread
// independent 1KB-contiguous X loads (the proven 7 TB/s pattern), W streamed
// per-thread-coalesced from L2 (bf16-packed, unpack = shl/and).
// Thread t: acc[r][n] += X[row r][k] * W[k][n] over k in {i*1024+4t+e}.
// Reduce: 64-lane butterfly per (r,n) + cross-wave LDS; non-atomic Hsum store.
// ---------------------------------------------------------------------------
__global__ __launch_bounds__(THR, 3) void mhc_gemm_kernel(
    const float* __restrict__ X, const uint4* __restrict__ Wq,
    float* __restrict__ Hsum)
{
    __shared__ float red[4][96];
    const int t = threadIdx.x, l = t & 63, wv = t >> 6;
    const int rowbase = blockIdx.x * RB;
    const float4* __restrict__ Xg = reinterpret_cast<const float4*>(X);

    float acc[RB][NC];
#pragma unroll
    for (int r = 0; r < RB; ++r)
#pragma unroll
        for (int n = 0; n < NC; ++n) acc[r][n] = 0.f;

    for (int i = 0; i < 8; ++i) {
        float4 xr[RB];
#pragma unroll
        for (int r = 0; r < RB; ++r)
            xr[r] = Xg[(size_t)(rowbase + r) * (K_DIM / 4) + i * 256 + t];

#pragma unroll
        for (int e = 0; e < 4; ++e) {
#pragma unroll
            for (int j4 = 0; j4 < 3; ++j4) {
                const uint4 w = Wq[(size_t)(((i << 2) + e) * 3 + j4) * 256 + t];
#pragma unroll
                for (int m = 0; m < 4; ++m) {
                    const uint32_t u = (&w.x)[m];
                    const float wlo = __uint_as_float(u << 16);
                    const float whi = __uint_as_float(u & 0xFFFF0000u);
                    const int n = j4 * 8 + 2 * m;
#pragma unroll
                    for (int r = 0; r < RB; ++r) {
                        const float xv = reinterpret_cast<const float*>(&xr[r])[e];
                        acc[r][n]     = fmaf(xv, wlo, acc[r][n]);
                        acc[r][n + 1] = fmaf(xv, whi, acc[r][n + 1]);
                    }
                }
            }
        }
    }

    // ---- reduce: butterfly each (r,n) across the wave, then across waves ----
    float v1 = 0.f, v2 = 0.f;
#pragma unroll
    for (int fl = 0; fl < 96; ++fl) {
        float v = acc[fl / NC][fl % NC];      // fl unroll-constant -> static
        v += __shfl_xor(v, 1);
        v += __shfl_xor(v, 2);
        v += __shfl_xor(v, 4);
        v += __shfl_xor(v, 8);
        v += __shfl_xor(v, 16);
        v += __shfl_xor(v, 32);
        if (l == fl) v1 = v;                  // fl in [0,64)
        if (l == fl - 64) v2 = v;             // fl in [64,96)
    }
    red[wv][l] = v1;
    if (l < 32) red[wv][64 + l] = v2;
    __syncthreads();

    if (t < 96) {
        const float h = red[0][t] + red[1][t] + red[2][t] + red[3][t];
        Hsum[(size_t)blockIdx.x * 96 + t] = h;   // = Hsum[(rowbase+r)*24+n]
    }
}

// ---------------------------------------------------------------------------
// Kernel 2: params (transform + sinkhorn) + apply. One block per row.
// ---------------------------------------------------------------------------
__global__ __launch_bounds__(256) void mhc_apply_kernel(
    const float* __restrict__ X, const float* __restrict__ Hsum,
    const float* __restrict__ ab, float* __restrict__ out)
{
    __shared__ float pbuf[NC];
    const int row = blockIdx.x;
    const int t = threadIdx.x;

    if (t < 64) {
        const int lane = t;
        const float pl = (lane < NC) ? Hsum[(size_t)row * NC + lane] : 0.f;
        const float bias  = (lane < NC) ? ab[lane] : 0.f;
        const float scale = ab[(lane < 16) ? 24 : ((lane < 20) ? 25 : 26)];

        float vout;
        if (lane < 16) {
            vout = __expf(fmaf(scale, pl, bias));                 // exp(a_res*H+b)
        } else {
            vout = fmaf(scale, 1.f / (1.f + __expf(-pl)), bias);  // a*sigmoid(H)+b
        }

        // Sinkhorn on lanes 0..15: lane = s*4 + i.
        float p = vout;
        for (int it = 0; it < 20; ++it) {
            float rs = p + __shfl_xor(p, 1);
            rs += __shfl_xor(rs, 2);
            p = p / rs;
            float cs = p + __shfl_xor(p, 4);
            cs += __shfl_xor(cs, 8);
            p = p / cs;
        }
        if (lane < NC) pbuf[lane] = (lane < 16) ? p : vout;
    }
    __syncthreads();

    float hres[4][4], hpre[4], hpos[4];
#pragma unroll
    for (int i = 0; i < 16; ++i) hres[i >> 2][i & 3] = pbuf[i];
#pragma unroll
    for (int i = 0; i < 4; ++i) hpre[i] = pbuf[16 + i];
#pragma unroll
    for (int i = 0; i < 4; ++i) hpos[i] = pbuf[20 + i];

    const float4* __restrict__ Xr =
        reinterpret_cast<const float4*>(X + (size_t)row * K_DIM);
    float4* __restrict__ Or = reinterpret_cast<float4*>(out + (size_t)row * K_DIM);

#pragma unroll
    for (int q = 0; q < 2; ++q) {
        const int pos = t + q * 256;          // float4 index within a 2048-seg
        float4 xq[4];
#pragma unroll
        for (int i = 0; i < 4; ++i) xq[i] = Xr[i * (D_DIM / 4) + pos];

        float y[4];
#pragma unroll
        for (int e = 0; e < 4; ++e) {
            float s = 0.f;
#pragma unroll
            for (int i = 0; i < 4; ++i)
                s = fmaf(hpre[i], reinterpret_cast<const float*>(&xq[i])[e], s);
            y[e] = s;
        }

#pragma unroll
        for (int s = 0; s < 4; ++s) {
            float4 o;
            float* oe = reinterpret_cast<float*>(&o);
#pragma unroll
            for (int e = 0; e < 4; ++e) {
                float v = hpos[s] * y[e];
#pragma unroll
                for (int i = 0; i < 4; ++i)
                    v = fmaf(hres[s][i], reinterpret_cast<const float*>(&xq[i])[e], v);
                oe[e] = v;
            }
            Or[s * (D_DIM / 4) + pos] = o;
        }
    }
}

extern "C" void kernel_launch(void* const* d_in, const int* in_sizes, int n_in,
                              void* d_out, int out_size, void* d_ws, size_t ws_size,
                              hipStream_t stream) {
    const float* X  = (const float*)d_in[0];
    const float* W  = (const float*)d_in[1];
    const float* ab = (const float*)d_in[2];
    float* out = (float*)d_out;
    uint4* Wq  = (uint4*)d_ws;                              // 393,216 B
    float* Hsum = (float*)((char*)d_ws + 393216);           // + 786,432 B

    mhc_prepack_kernel<<<K_DIM / 256, 256, 0, stream>>>(W, Wq);
    mhc_gemm_kernel<<<M_ROWS / RB, THR, 0, stream>>>(X, Wq, Hsum);
    mhc_apply_kernel<<<M_ROWS, 256, 0, stream>>>(X, Hsum, ab, out);
}

// Round 20
// 235.495 us; speedup vs baseline: 1.6499x; 1.6499x over previous
//
#include <hip/hip_runtime.h>
#include <math.h>
#include <stdint.h>

#define K_DIM 8192     // S*DIM
#define D_DIM 2048
#define M_ROWS 8192
#define N_W 32         // W columns (only 24 used in H)
#define NC 24
#define RB 4           // rows per block (gemm)
#define THR 256

typedef float f32x4 __attribute__((ext_vector_type(4)));

// Wq layout (uint4): [g(96)][t(256)], g = (i*4+e)*3 + j4.
// Thread t's k-set: k = i*1024 + 4t + e (i<8, e<4). Entry (g,t) packs W cols
// [j4*8 .. j4*8+7] of row k as 4 u32 (2 rne-bf16 each: low16=col 2m,
// high16=col 2m+1). Consecutive t -> consecutive uint4 = coalesced L2 stream.
// Total 96*256*16B = 393,216 B (L2-resident).

// ---------------------------------------------------------------------------
// Kernel 0: prepack W -> packed rne-bf16 pairs, thread per k.
// ---------------------------------------------------------------------------
__global__ __launch_bounds__(256) void mhc_prepack_kernel(
    const float* __restrict__ W, uint4* __restrict__ Wq)
{
    const int k = blockIdx.x * 256 + threadIdx.x;   // 0..8191
    const int i = k >> 10, e = k & 3, t = (k >> 2) & 255;
    const float* wr = W + (size_t)k * N_W;
#pragma unroll
    for (int j4 = 0; j4 < 3; ++j4) {
        uint32_t u[4];
#pragma unroll
        for (int m = 0; m < 4; ++m) {
            uint32_t a = __float_as_uint(wr[j4 * 8 + 2 * m]);
            uint32_t b = __float_as_uint(wr[j4 * 8 + 2 * m + 1]);
            a = a + 0x7FFFu + ((a >> 16) & 1u);     // rne to bf16
            b = b + 0x7FFFu + ((b >> 16) & 1u);
            u[m] = (b & 0xFFFF0000u) | (a >> 16);
        }
        Wq[(size_t)(((i * 4 + e) * 3) + j4) * 256 + t] =
            make_uint4(u[0], u[1], u[2], u[3]);
    }
}

// ---------------------------------------------------------------------------
// Kernel 1: H[m,0:24] = X @ W (W rne-bf16, X exact f32) — APPLY-SHAPED:
// 2048 blocks x 256 thr, no LDS/barriers in the hot loop, per-thread
// independent 1KB-contiguous X loads (the proven 7 TB/s pattern), W streamed
// per-thread-coalesced from L2 (bf16-packed, unpack = shl/and).
// R20 fix vs R19: NO min-occupancy demand in __launch_bounds__ — R19's
// (256,3) capped VGPR at 84 < the ~130 live, spilling acc to scratch
// (WRITE_SIZE showed 505 MB of spill). Unconstrained alloc -> zero spill;
// #pragma unroll 2 on the i-loop lets next-chunk loads issue under the
// current chunk's FMA chain (barrier-free ILP instead of occupancy).
// Reduce: 64-lane butterfly per (r,n) + cross-wave LDS; non-atomic store.
// ---------------------------------------------------------------------------
__global__ __launch_bounds__(THR) void mhc_gemm_kernel(
    const float* __restrict__ X, const uint4* __restrict__ Wq,
    float* __restrict__ Hsum)
{
    __shared__ float red[4][96];
    const int t = threadIdx.x, l = t & 63, wv = t >> 6;
    const int rowbase = blockIdx.x * RB;
    const float4* __restrict__ Xg = reinterpret_cast<const float4*>(X);

    float acc[RB][NC];
#pragma unroll
    for (int r = 0; r < RB; ++r)
#pragma unroll
        for (int n = 0; n < NC; ++n) acc[r][n] = 0.f;

#pragma unroll 2
    for (int i = 0; i < 8; ++i) {
        float4 xr[RB];
#pragma unroll
        for (int r = 0; r < RB; ++r)
            xr[r] = Xg[(size_t)(rowbase + r) * (K_DIM / 4) + i * 256 + t];

#pragma unroll
        for (int e = 0; e < 4; ++e) {
#pragma unroll
            for (int j4 = 0; j4 < 3; ++j4) {
                const uint4 w = Wq[(size_t)(((i << 2) + e) * 3 + j4) * 256 + t];
#pragma unroll
                for (int m = 0; m < 4; ++m) {
                    const uint32_t u = (&w.x)[m];
                    const float wlo = __uint_as_float(u << 16);
                    const float whi = __uint_as_float(u & 0xFFFF0000u);
                    const int n = j4 * 8 + 2 * m;
#pragma unroll
                    for (int r = 0; r < RB; ++r) {
                        const float xv = reinterpret_cast<const float*>(&xr[r])[e];
                        acc[r][n]     = fmaf(xv, wlo, acc[r][n]);
                        acc[r][n + 1] = fmaf(xv, whi, acc[r][n + 1]);
                    }
                }
            }
        }
    }

    // ---- reduce: butterfly each (r,n) across the wave, then across waves ----
    float v1 = 0.f, v2 = 0.f;
#pragma unroll
    for (int fl = 0; fl < 96; ++fl) {
        float v = acc[fl / NC][fl % NC];      // fl unroll-constant -> static
        v += __shfl_xor(v, 1);
        v += __shfl_xor(v, 2);
        v += __shfl_xor(v, 4);
        v += __shfl_xor(v, 8);
        v += __shfl_xor(v, 16);
        v += __shfl_xor(v, 32);
        if (l == fl) v1 = v;                  // fl in [0,64)
        if (l == fl - 64) v2 = v;             // fl in [64,96)
    }
    red[wv][l] = v1;
    if (l < 32) red[wv][64 + l] = v2;
    __syncthreads();

    if (t < 96) {
        const float h = red[0][t] + red[1][t] + red[2][t] + red[3][t];
        Hsum[(size_t)blockIdx.x * 96 + t] = h;   // = Hsum[(rowbase+r)*24+n]
    }
}

// ---------------------------------------------------------------------------
// Kernel 2: params (transform + sinkhorn) + apply. One block per row.
// ---------------------------------------------------------------------------
__global__ __launch_bounds__(256) void mhc_apply_kernel(
    const float* __restrict__ X, const float* __restrict__ Hsum,
    const float* __restrict__ ab, float* __restrict__ out)
{
    __shared__ float pbuf[NC];
    const int row = blockIdx.x;
    const int t = threadIdx.x;

    if (t < 64) {
        const int lane = t;
        const float pl = (lane < NC) ? Hsum[(size_t)row * NC + lane] : 0.f;
        const float bias  = (lane < NC) ? ab[lane] : 0.f;
        const float scale = ab[(lane < 16) ? 24 : ((lane < 20) ? 25 : 26)];

        float vout;
        if (lane < 16) {
            vout = __expf(fmaf(scale, pl, bias));                 // exp(a_res*H+b)
        } else {
            vout = fmaf(scale, 1.f / (1.f + __expf(-pl)), bias);  // a*sigmoid(H)+b
        }

        // Sinkhorn on lanes 0..15: lane = s*4 + i.
        float p = vout;
        for (int it = 0; it < 20; ++it) {
            float rs = p + __shfl_xor(p, 1);
            rs += __shfl_xor(rs, 2);
            p = p / rs;
            float cs = p + __shfl_xor(p, 4);
            cs += __shfl_xor(cs, 8);
            p = p / cs;
        }
        if (lane < NC) pbuf[lane] = (lane < 16) ? p : vout;
    }
    __syncthreads();

    float hres[4][4], hpre[4], hpos[4];
#pragma unroll
    for (int i = 0; i < 16; ++i) hres[i >> 2][i & 3] = pbuf[i];
#pragma unroll
    for (int i = 0; i < 4; ++i) hpre[i] = pbuf[16 + i];
#pragma unroll
    for (int i = 0; i < 4; ++i) hpos[i] = pbuf[20 + i];

    const float4* __restrict__ Xr =
        reinterpret_cast<const float4*>(X + (size_t)row * K_DIM);
    float4* __restrict__ Or = reinterpret_cast<float4*>(out + (size_t)row * K_DIM);

#pragma unroll
    for (int q = 0; q < 2; ++q) {
        const int pos = t + q * 256;          // float4 index within a 2048-seg
        float4 xq[4];
#pragma unroll
        for (int i = 0; i < 4; ++i) xq[i] = Xr[i * (D_DIM / 4) + pos];

        float y[4];
#pragma unroll
        for (int e = 0; e < 4; ++e) {
            float s = 0.f;
#pragma unroll
            for (int i = 0; i < 4; ++i)
                s = fmaf(hpre[i], reinterpret_cast<const float*>(&xq[i])[e], s);
            y[e] = s;
        }

#pragma unroll
        for (int s = 0; s < 4; ++s) {
            float4 o;
            float* oe = reinterpret_cast<float*>(&o);
#pragma unroll
            for (int e = 0; e < 4; ++e) {
                float v = hpos[s] * y[e];
#pragma unroll
                for (int i = 0; i < 4; ++i)
                    v = fmaf(hres[s][i], reinterpret_cast<const float*>(&xq[i])[e], v);
                oe[e] = v;
            }
            Or[s * (D_DIM / 4) + pos] = o;
        }
    }
}

extern "C" void kernel_launch(void* const* d_in, const int* in_sizes, int n_in,
                              void* d_out, int out_size, void* d_ws, size_t ws_size,
                              hipStream_t stream) {
    const float* X  = (const float*)d_in[0];
    const float* W  = (const float*)d_in[1];
    const float* ab = (const float*)d_in[2];
    float* out = (float*)d_out;
    uint4* Wq  = (uint4*)d_ws;                              // 393,216 B
    float* Hsum = (float*)((char*)d_ws + 393216);           // + 786,432 B

    mhc_prepack_kernel<<<K_DIM / 256, 256, 0, stream>>>(W, Wq);
    mhc_gemm_kernel<<<M_ROWS / RB, THR, 0, stream>>>(X, Wq, Hsum);
    mhc_apply_kernel<<<M_ROWS, 256, 0, stream>>>(X, Hsum, ab, out);
}

// Round 21
// 185.725 us; speedup vs baseline: 2.0920x; 1.2680x over previous
//
#include <hip/hip_runtime.h>
#include <math.h>
#include <stdint.h>

#define K_DIM 8192     // S*DIM
#define D_DIM 2048
#define M_ROWS 8192
#define N_W 32         // W columns (only 24 used)
#define NC 24
#define ROWS 4         // rows per block
#define THR 256        // 4 waves; wave wv owns cols [6wv, 6wv+6)

typedef float f32x4 __attribute__((ext_vector_type(4)));

// Wq2 layout (u32): [g(128)][wv(4)][w(3)][l(64)], g = i*4+e for k=i*256+l*4+e.
// Word (g,wv,w,l) packs rne-bf16 of W[k][6wv+2w] (low16) and W[k][6wv+2w+1]
// (high16). A wave's load of word w is 256B contiguous -> coalesced.
// Total 128*4*3*64*4B = 393,216 B (L2-resident).

// ---------------------------------------------------------------------------
// Kernel 0: prepack W -> packed rne-bf16 col-pairs, thread per k.
// ---------------------------------------------------------------------------
__global__ __launch_bounds__(256) void mhc_prepack_kernel(
    const float* __restrict__ W, uint32_t* __restrict__ Wq2)
{
    const int k = blockIdx.x * 256 + threadIdx.x;   // 0..8191
    const int i = k >> 8, l = (k >> 2) & 63, e = k & 3;
    const int g = i * 4 + e;
    const float* wr = W + (size_t)k * N_W;
#pragma unroll
    for (int wv = 0; wv < 4; ++wv) {
#pragma unroll
        for (int w = 0; w < 3; ++w) {
            const int c0 = wv * 6 + 2 * w;
            uint32_t a = __float_as_uint(wr[c0]);
            uint32_t b = __float_as_uint(wr[c0 + 1]);
            a = a + 0x7FFFu + ((a >> 16) & 1u);   // rne -> bf16
            b = b + 0x7FFFu + ((b >> 16) & 1u);
            Wq2[(size_t)(((g * 4 + wv) * 3) + w) * 64 + l] =
                (b & 0xFFFF0000u) | (a >> 16);
        }
    }
}

// ---------------------------------------------------------------------------
// FUSED kernel. Block = 256 thr (4 waves) owns 4 rows; 2048 blocks.
//  Phase 1 (gemm, col-split): wave wv computes H[*][6wv..6wv+6) over FULL K.
//    Lane l, iter i: k-set {i*256+4l+e}; 4x 1KB-contiguous X wave-loads
//    (all 4 waves read the tile; redundancy served by L1/L2), 3x 256B W
//    wave-loads. acc[4][6]=24 regs, W=12, X=16 -> deep pipelining, no spill
//    (R20's failure: acc 96 + loads 64 > allocatable).
//  Phase 2: 6-step butterfly per (r,c) -> lane r*6+c writes Hf[r][6wv+c].
//    No cross-wave reduce (cols disjoint). 1 barrier.
//  Phase 3: wave 0: transform + 20-iter Sinkhorn, 4 rows in 16-lane groups
//    (R6-validated maps) -> pbuf. 1 barrier.
//  Phase 4 (apply): all 256 thr, X re-read is L2-hot (just touched);
//    coalesced O stores. H = X@W with W rne-bf16 (absmax 0.031 validated).
// No atomics, no part buffer, no Hsum round-trip.
// ---------------------------------------------------------------------------
__global__ __launch_bounds__(THR) void mhc_fused_kernel(
    const float* __restrict__ X, const uint32_t* __restrict__ Wq2,
    const float* __restrict__ ab, float* __restrict__ out)
{
    __shared__ float Hf[ROWS * NC];     // 384 B
    __shared__ float pbuf[ROWS * NC];   // 384 B

    const int t = threadIdx.x, l = t & 63, wv = t >> 6;
    const int rowbase = blockIdx.x * ROWS;
    const float4* __restrict__ Xg = reinterpret_cast<const float4*>(X);

    // ---- phase 1: col-split gemm ----
    float acc[ROWS][6];
#pragma unroll
    for (int r = 0; r < ROWS; ++r)
#pragma unroll
        for (int c = 0; c < 6; ++c) acc[r][c] = 0.f;

#pragma unroll 2
    for (int i = 0; i < 32; ++i) {
        float4 xr[ROWS];
#pragma unroll
        for (int r = 0; r < ROWS; ++r)
            xr[r] = Xg[(size_t)(rowbase + r) * (K_DIM / 4) + i * 64 + l];

#pragma unroll
        for (int e = 0; e < 4; ++e) {
            uint32_t wreg[3];
#pragma unroll
            for (int w = 0; w < 3; ++w)
                wreg[w] = Wq2[(size_t)((((i * 4 + e) * 4 + wv) * 3) + w) * 64 + l];
#pragma unroll
            for (int w = 0; w < 3; ++w) {
                const float wlo = __uint_as_float(wreg[w] << 16);
                const float whi = __uint_as_float(wreg[w] & 0xFFFF0000u);
#pragma unroll
                for (int r = 0; r < ROWS; ++r) {
                    const float xv = reinterpret_cast<const float*>(&xr[r])[e];
                    acc[r][2 * w]     = fmaf(xv, wlo, acc[r][2 * w]);
                    acc[r][2 * w + 1] = fmaf(xv, whi, acc[r][2 * w + 1]);
                }
            }
        }
    }

    // ---- phase 2: butterfly reduce; lane r*6+c -> Hf[r][6wv+c] ----
    float mine = 0.f;
#pragma unroll
    for (int fl = 0; fl < 24; ++fl) {
        float v = acc[fl / 6][fl % 6];        // fl unroll-constant -> static
        v += __shfl_xor(v, 1);
        v += __shfl_xor(v, 2);
        v += __shfl_xor(v, 4);
        v += __shfl_xor(v, 8);
        v += __shfl_xor(v, 16);
        v += __shfl_xor(v, 32);
        if (l == fl) mine = v;
    }
    if (l < 24) Hf[(l / 6) * NC + wv * 6 + (l % 6)] = mine;
    __syncthreads();

    // ---- phase 3: transform + sinkhorn on wave 0 (4 rows in parallel) ----
    if (wv == 0) {
        const int row = l >> 4, idx = l & 15;
        float p = __expf(fmaf(ab[24], Hf[row * NC + idx], ab[idx]));

        if (l < 32) {
            const int rr = l >> 3, ci = 16 + (l & 7);
            const float sc = (ci < 20) ? ab[25] : ab[26];
            pbuf[rr * NC + ci] =
                fmaf(sc, 1.f / (1.f + __expf(-Hf[rr * NC + ci])), ab[ci]);
        }

        // lane idx = s*4+i; axis=-1 sum = xor 1,2 ; axis=-2 sum = xor 4,8
        for (int it = 0; it < 20; ++it) {
            float rs = p + __shfl_xor(p, 1);
            rs += __shfl_xor(rs, 2);
            p = p / rs;
            float cs = p + __shfl_xor(p, 4);
            cs += __shfl_xor(cs, 8);
            p = p / cs;
        }
        pbuf[row * NC + idx] = p;
    }
    __syncthreads();

    // ---- phase 4: apply (X re-read L2-hot), coalesced O stores ----
    float4* __restrict__ Og = reinterpret_cast<float4*>(out);
#pragma unroll
    for (int r = 0; r < ROWS; ++r) {
        const float* pr = &pbuf[r * NC];
        float hre[4][4], hpr[4], hpo[4];
#pragma unroll
        for (int q = 0; q < 16; ++q) hre[q >> 2][q & 3] = pr[q];
#pragma unroll
        for (int q = 0; q < 4; ++q) hpr[q] = pr[16 + q];
#pragma unroll
        for (int q = 0; q < 4; ++q) hpo[q] = pr[20 + q];

        const size_t rb4 = (size_t)(rowbase + r) * (K_DIM / 4);
#pragma unroll
        for (int q = 0; q < 2; ++q) {
            const int pos = q * 256 + t;
            float4 xq[4];
#pragma unroll
            for (int i = 0; i < 4; ++i) xq[i] = Xg[rb4 + i * 512 + pos];

            float y[4];
#pragma unroll
            for (int e = 0; e < 4; ++e) {
                float v = 0.f;
#pragma unroll
                for (int i = 0; i < 4; ++i)
                    v = fmaf(hpr[i], reinterpret_cast<const float*>(&xq[i])[e], v);
                y[e] = v;
            }

#pragma unroll
            for (int s = 0; s < 4; ++s) {
                float4 o;
                float* oe = reinterpret_cast<float*>(&o);
#pragma unroll
                for (int e = 0; e < 4; ++e) {
                    float v = hpo[s] * y[e];
#pragma unroll
                    for (int i = 0; i < 4; ++i)
                        v = fmaf(hre[s][i],
                                 reinterpret_cast<const float*>(&xq[i])[e], v);
                    oe[e] = v;
                }
                Og[rb4 + s * 512 + pos] = o;
            }
        }
    }
}

extern "C" void kernel_launch(void* const* d_in, const int* in_sizes, int n_in,
                              void* d_out, int out_size, void* d_ws, size_t ws_size,
                              hipStream_t stream) {
    const float* X  = (const float*)d_in[0];
    const float* W  = (const float*)d_in[1];
    const float* ab = (const float*)d_in[2];
    float* out = (float*)d_out;
    uint32_t* Wq2 = (uint32_t*)d_ws;   // 393,216 B

    mhc_prepack_kernel<<<K_DIM / 256, 256, 0, stream>>>(W, Wq2);
    mhc_fused_kernel<<<M_ROWS / ROWS, THR, 0, stream>>>(X, Wq2, ab, out);
}

// Round 22
// 166.391 us; speedup vs baseline: 2.3351x; 1.1162x over previous
//
#include <hip/hip_runtime.h>
#include <math.h>
#include <stdint.h>

#define K_DIM 8192     // S*DIM
#define D_DIM 2048
#define M_ROWS 8192
#define N_W 32         // W columns (only 24 used in H)
#define NC 24
#define KSPLIT 4       // grid.y; 2048 k per block
#define ROWS 16        // rows per block = one MFMA tile
#define THR 64         // ONE wave per block
#define CCOL 256       // cols per chunk (16 rows x 1KB runs = 16KB)
#define NCH 8          // chunks per block (8 x 256 = 2048 k)
#define KSC 8          // ksteps (32 k) per chunk

typedef short bf16x8 __attribute__((ext_vector_type(8)));
typedef float f32x4 __attribute__((ext_vector_type(4)));
union U32x4 { uint32_t u[4]; bf16x8 v; };

typedef const uint32_t __attribute__((address_space(1)))* gas_ptr;
typedef uint32_t __attribute__((address_space(3)))* las_ptr;

// wfrag (u16, W rne-bf16 hi-only): [ks(256)][tile(2)][lane(64)][e(8)] = 512 KB.
#define WFI(ks, tile) (((ks) * 2 + (tile)) * 64)   // bf16x8 units

// ---------------------------------------------------------------------------
// Kernel 0: prepack W -> rne bf16 B-fragments (once).
// k-map matches A-frag map: lane=((k&31)>>3)*16+(n&15), e=k&7 (same perm on
// both MFMA operands so it cancels; only C/D layout matters).
// ---------------------------------------------------------------------------
__global__ __launch_bounds__(256) void mhc_prepack_kernel(
    const float* __restrict__ W, unsigned short* __restrict__ wfrag)
{
    const int idx = blockIdx.x * 256 + threadIdx.x;   // 0 .. 262143
    const int k = idx >> 5, n = idx & 31;
    const float w = W[(size_t)k * N_W + n];
    const uint32_t u = __float_as_uint(w);
    const uint32_t r = u + 0x7FFFu + ((u >> 16) & 1u);   // round-nearest-even

    const int ks = k >> 5, kk = k & 31;
    const int lane = ((kk >> 3) << 4) | (n & 15);
    const int e = kk & 7;
    const int tile = n >> 4;
    wfrag[((size_t)WFI(ks, tile) + lane) * 8 + e] = (unsigned short)(r >> 16);
}

// ---------------------------------------------------------------------------
// Kernel 1: partial H via MFMA, H = Xhi@W + Xlo@W.  (R15 configuration —
// best measured: total 164.8 us.)  X read in 1KB-contiguous runs via
// global_load_lds -> linear LDS [16][256], double-buffered per wave, one
// wave per block, counted vmcnt(16), sched_barrier fences (rule #18).
// No barriers, no atomics: partial store to part[ksplit]; apply reduces.
// C/D: D[row=(l>>4)*4+reg][col=l&15]  [HW-verified].
// ---------------------------------------------------------------------------
__global__ __launch_bounds__(THR) void mhc_gemm_kernel(
    const float* __restrict__ X, const unsigned short* __restrict__ wfrag,
    float* __restrict__ part)
{
    __shared__ __align__(16) float Xl[2][ROWS * CCOL];   // 2 x 16 KB
    const int l = threadIdx.x;
    const int rowbase = blockIdx.x * ROWS;
    const int colbase = blockIdx.y * (K_DIM / KSPLIT);
    const int ks00 = blockIdx.y * (K_DIM / KSPLIT / 32);

    const bf16x8* __restrict__ wf = reinterpret_cast<const bf16x8*>(wfrag);

    f32x4 c0 = {0.f, 0.f, 0.f, 0.f};
    f32x4 c1 = {0.f, 0.f, 0.f, 0.f};

    // ---- issue chunk 0's X loads (16 x 1KB contiguous) ----
#pragma unroll
    for (int r = 0; r < ROWS; ++r) {
        const float* src = X + (size_t)(rowbase + r) * K_DIM + colbase + l * 4;
        __builtin_amdgcn_global_load_lds((gas_ptr)src, (las_ptr)&Xl[0][r * CCOL],
                                         16, 0, 0);
    }

#pragma unroll
    for (int c = 0; c < NCH; ++c) {
        // ---- B-loads for chunk c (issued BEFORE next-chunk X: vmcnt order) --
        bf16x8 b0[KSC], b1[KSC];
#pragma unroll
        for (int s = 0; s < KSC; ++s) {
            const int ks = ks00 + c * KSC + s;
            b0[s] = wf[WFI(ks, 0) + l];
            b1[s] = wf[WFI(ks, 1) + l];
        }
        __builtin_amdgcn_sched_barrier(0);

        // ---- issue chunk c+1's X loads into the other buffer ----
        if (c + 1 < NCH) {
#pragma unroll
            for (int r = 0; r < ROWS; ++r) {
                const float* src = X + (size_t)(rowbase + r) * K_DIM
                                   + colbase + (c + 1) * CCOL + l * 4;
                __builtin_amdgcn_global_load_lds(
                    (gas_ptr)src, (las_ptr)&Xl[(c + 1) & 1][r * CCOL], 16, 0, 0);
            }
            __builtin_amdgcn_sched_barrier(0);
            asm volatile("s_waitcnt vmcnt(16)" ::: "memory");
        } else {
            __builtin_amdgcn_sched_barrier(0);
            asm volatile("s_waitcnt vmcnt(0)" ::: "memory");
        }
        __builtin_amdgcn_sched_barrier(0);   // rule #18: fence ds_read hoisting

        // ---- compute chunk c: 8 ksteps x (2 ds_read_b128 + pack + 4 MFMA) --
        const float* xt = &Xl[c & 1][(l & 15) * CCOL + ((l >> 4) << 3)];
#pragma unroll
        for (int s = 0; s < KSC; ++s) {
            const float4 xa = *reinterpret_cast<const float4*>(xt + s * 32);
            const float4 xb = *reinterpret_cast<const float4*>(xt + s * 32 + 4);
            float xs[8];
            xs[0] = xa.x; xs[1] = xa.y; xs[2] = xa.z; xs[3] = xa.w;
            xs[4] = xb.x; xs[5] = xb.y; xs[6] = xb.z; xs[7] = xb.w;

            U32x4 ah, al;
#pragma unroll
            for (int p = 0; p < 4; ++p) {
                const uint32_t u0 = __float_as_uint(xs[2 * p]);
                const uint32_t u1 = __float_as_uint(xs[2 * p + 1]);
                const float h0 = __uint_as_float(u0 & 0xFFFF0000u);
                const float h1 = __uint_as_float(u1 & 0xFFFF0000u);
                const uint32_t r0 = __float_as_uint(xs[2 * p] - h0);
                const uint32_t r1 = __float_as_uint(xs[2 * p + 1] - h1);
                ah.u[p] = (u1 & 0xFFFF0000u) | (u0 >> 16);
                al.u[p] = (r1 & 0xFFFF0000u) | (r0 >> 16);
            }

            c0 = __builtin_amdgcn_mfma_f32_16x16x32_bf16(ah.v, b0[s], c0, 0, 0, 0);
            c0 = __builtin_amdgcn_mfma_f32_16x16x32_bf16(al.v, b0[s], c0, 0, 0, 0);
            c1 = __builtin_amdgcn_mfma_f32_16x16x32_bf16(ah.v, b1[s], c1, 0, 0, 0);
            c1 = __builtin_amdgcn_mfma_f32_16x16x32_bf16(al.v, b1[s], c1, 0, 0, 0);
        }
    }

    // ---- non-atomic partial store: part[by][row][col] ----
    float* prow = part + ((size_t)blockIdx.y * M_ROWS + rowbase) * NC;
    const int drow0 = (l >> 4) << 2;
    const int col = l & 15;
#pragma unroll
    for (int r = 0; r < 4; ++r)
        prow[(drow0 + r) * NC + col] = c0[r];
    if (col < 8) {
#pragma unroll
        for (int r = 0; r < 4; ++r)
            prow[(drow0 + r) * NC + 16 + col] = c1[r];
    }
}

// ---------------------------------------------------------------------------
// Kernel 2: reduce partials + params (transform + sinkhorn) + apply.
// One block per row.
// ---------------------------------------------------------------------------
__global__ __launch_bounds__(256) void mhc_apply_kernel(
    const float* __restrict__ X, const float* __restrict__ part,
    const float* __restrict__ ab, float* __restrict__ out)
{
    __shared__ float pbuf[NC];
    const int row = blockIdx.x;
    const int t = threadIdx.x;

    if (t < 64) {
        const int lane = t;
        float pl = 0.f;
        if (lane < NC) {
#pragma unroll
            for (int j = 0; j < KSPLIT; ++j)
                pl += part[((size_t)j * M_ROWS + row) * NC + lane];
        }
        const float bias  = (lane < NC) ? ab[lane] : 0.f;
        const float scale = ab[(lane < 16) ? 24 : ((lane < 20) ? 25 : 26)];

        float vout;
        if (lane < 16) {
            vout = __expf(fmaf(scale, pl, bias));                 // exp(a_res*H+b)
        } else {
            vout = fmaf(scale, 1.f / (1.f + __expf(-pl)), bias);  // a*sigmoid(H)+b
        }

        // Sinkhorn on lanes 0..15: lane = s*4 + i.
        float p = vout;
        for (int it = 0; it < 20; ++it) {
            float rs = p + __shfl_xor(p, 1);
            rs += __shfl_xor(rs, 2);
            p = p / rs;
            float cs = p + __shfl_xor(p, 4);
            cs += __shfl_xor(cs, 8);
            p = p / cs;
        }
        if (lane < NC) pbuf[lane] = (lane < 16) ? p : vout;
    }
    __syncthreads();

    float hres[4][4], hpre[4], hpos[4];
#pragma unroll
    for (int i = 0; i < 16; ++i) hres[i >> 2][i & 3] = pbuf[i];
#pragma unroll
    for (int i = 0; i < 4; ++i) hpre[i] = pbuf[16 + i];
#pragma unroll
    for (int i = 0; i < 4; ++i) hpos[i] = pbuf[20 + i];

    const float4* __restrict__ Xr =
        reinterpret_cast<const float4*>(X + (size_t)row * K_DIM);
    float4* __restrict__ Or = reinterpret_cast<float4*>(out + (size_t)row * K_DIM);

#pragma unroll
    for (int q = 0; q < 2; ++q) {
        const int pos = t + q * 256;          // float4 index within a 2048-seg
        float4 xq[4];
#pragma unroll
        for (int i = 0; i < 4; ++i) xq[i] = Xr[i * (D_DIM / 4) + pos];

        float y[4];
#pragma unroll
        for (int e = 0; e < 4; ++e) {
            float s = 0.f;
#pragma unroll
            for (int i = 0; i < 4; ++i)
                s = fmaf(hpre[i], reinterpret_cast<const float*>(&xq[i])[e], s);
            y[e] = s;
        }

#pragma unroll
        for (int s = 0; s < 4; ++s) {
            float4 o;
            float* oe = reinterpret_cast<float*>(&o);
#pragma unroll
            for (int e = 0; e < 4; ++e) {
                float v = hpos[s] * y[e];
#pragma unroll
                for (int i = 0; i < 4; ++i)
                    v = fmaf(hres[s][i], reinterpret_cast<const float*>(&xq[i])[e], v);
                oe[e] = v;
            }
            Or[s * (D_DIM / 4) + pos] = o;
        }
    }
}

extern "C" void kernel_launch(void* const* d_in, const int* in_sizes, int n_in,
                              void* d_out, int out_size, void* d_ws, size_t ws_size,
                              hipStream_t stream) {
    const float* X  = (const float*)d_in[0];
    const float* W  = (const float*)d_in[1];
    const float* ab = (const float*)d_in[2];
    float* out = (float*)d_out;
    unsigned short* wfrag = (unsigned short*)d_ws;          // 524,288 B
    float* part = (float*)((char*)d_ws + 524288);           // + 3,145,728 B

    mhc_prepack_kernel<<<(K_DIM * N_W) / 256, 256, 0, stream>>>(W, wfrag);
    dim3 g1(M_ROWS / ROWS, KSPLIT);
    mhc_gemm_kernel<<<g1, THR, 0, stream>>>(X, wfrag, part);
    mhc_apply_kernel<<<M_ROWS, 256, 0, stream>>>(X, part, ab, out);
}